// Round 3
// baseline (115.418 us; speedup 1.0000x reference)
//
#include <hip/hip_runtime.h>

// CategoryDense: out[b,c,o] = sum_i x[b,c,i] * kernel[c,i,o] + bias[c,o]
// B=8192, C=64, IN=64, OUT=64, fp32.
// Structure: block = (category c, 256-batch tile). kernel[c] staged to LDS
// (16KB, linear, global_load_lds). x staged in KC=16 chunks, double-buffered,
// via global_load_lds with PRE-SWIZZLED global source (rule #21: linear LDS
// dest + inverse-swizzled source + swizzled read = same involution).
// Swizzle: granule (b, jpos) holds source chunk jpos ^ ((b>>3)&3) so that
// compute-side reads (fixed r, jj; tb varying across lanes) spread 2-way
// across bank quads (free per m136).

constexpr int C_   = 64;
constexpr int IN_  = 64;
constexpr int OUT_ = 64;
constexpr int BT   = 256;           // batch tile per block
constexpr int KC   = 16;            // K chunk
constexpr int NCH  = IN_ / KC;      // 4 chunks

typedef float f32x4_t __attribute__((ext_vector_type(4)));

typedef __attribute__((address_space(1))) const void gvoid_t;
typedef __attribute__((address_space(3))) void lvoid_t;

__device__ __forceinline__ void gl_lds16(const float* g, float* l) {
    __builtin_amdgcn_global_load_lds((gvoid_t*)g, (lvoid_t*)l, 16, 0, 0);
}

__global__ __launch_bounds__(256)
void cat_dense_f32(const float* __restrict__ x,
                   const float* __restrict__ k,
                   const float* __restrict__ bias,
                   float* __restrict__ out) {
    __shared__ float ks[IN_ * OUT_];     // 16 KB, linear row-major k[c][i][o]
    __shared__ float xs[2][BT * KC];     // 2 x 16 KB

    const int tid  = threadIdx.x;
    const int wv   = tid >> 6;           // wave 0..3
    const int lane = tid & 63;
    const int c    = blockIdx.x & 63;
    const long bBase = (long)(blockIdx.x >> 6) * BT;

    const int to = tid & 7;              // output slice [to*8, to*8+8)
    const int tb = tid >> 3;             // batch slice  [tb*8, tb*8+8), 0..31

    // Per-lane pre-swizzled x source pointers for the 4 gload_lds per wave.
    // granule g = wv*256 + it*64 + lane; b = g>>2; jpos = g&3;
    // source chunk jsrc = jpos ^ ((b>>3)&3)  (XOR involution)
    const float* xsrc[4];
    #pragma unroll
    for (int it = 0; it < 4; ++it) {
        int g = wv * 256 + it * 64 + lane;
        int b = g >> 2, jpos = g & 3;
        int jsrc = jpos ^ ((b >> 3) & 3);
        xsrc[it] = x + (size_t)(bBase + b) * (C_ * IN_) + c * IN_ + 4 * jsrc;
    }

    // Stage kernel[c] (linear) + x chunk 0 into buf 0 — all async DMA.
    #pragma unroll
    for (int it = 0; it < 4; ++it) {
        int gb = wv * 256 + it * 64;     // base granule (wave-uniform)
        gl_lds16(k + (size_t)c * (IN_ * OUT_) + (size_t)(gb + lane) * 4,
                 &ks[gb * 4]);
    }
    #pragma unroll
    for (int it = 0; it < 4; ++it)
        gl_lds16(xsrc[it], &xs[0][(wv * 256 + it * 64) * 4]);

    float acc[8][8];
    #pragma unroll
    for (int r = 0; r < 8; ++r)
        #pragma unroll
        for (int q = 0; q < 8; ++q) acc[r][q] = 0.f;

    const float4* ksv = (const float4*)ks;

    #pragma unroll
    for (int t = 0; t < NCH; ++t) {
        __syncthreads();   // vmcnt(0): buf[t&1] staged; prev readers of buf[(t+1)&1] done
        if (t + 1 < NCH) { // prefetch next chunk into the other buffer
            #pragma unroll
            for (int it = 0; it < 4; ++it)
                gl_lds16(xsrc[it] + (t + 1) * KC,
                         &xs[(t + 1) & 1][(wv * 256 + it * 64) * 4]);
        }
        const float4* xv4 = (const float4*)xs[t & 1];
        const int kk = t * KC;

        #pragma unroll
        for (int jj = 0; jj < 4; ++jj) {
            // k rows i = kk + jj*4 + e, this thread's 8-output slice (2-way conflict, free)
            float4 kv0[4], kv1[4];
            #pragma unroll
            for (int e = 0; e < 4; ++e) {
                int i = kk + jj * 4 + e;
                kv0[e] = ksv[i * (OUT_ / 4) + to * 2];
                kv1[e] = ksv[i * (OUT_ / 4) + to * 2 + 1];
            }
            #pragma unroll
            for (int r = 0; r < 8; ++r) {
                // swizzled read: source chunk jj of row b=tb*8+r sits at jpos = jj ^ (tb&3)
                float4 xv = xv4[(tb * 8 + r) * 4 + (jj ^ (tb & 3))];
                float xe[4] = {xv.x, xv.y, xv.z, xv.w};
                #pragma unroll
                for (int e = 0; e < 4; ++e) {
                    acc[r][0] += xe[e] * kv0[e].x;
                    acc[r][1] += xe[e] * kv0[e].y;
                    acc[r][2] += xe[e] * kv0[e].z;
                    acc[r][3] += xe[e] * kv0[e].w;
                    acc[r][4] += xe[e] * kv1[e].x;
                    acc[r][5] += xe[e] * kv1[e].y;
                    acc[r][6] += xe[e] * kv1[e].z;
                    acc[r][7] += xe[e] * kv1[e].w;
                }
            }
        }
    }

    // epilogue: bias + nontemporal stores (don't evict x from L3)
    float4 bv0 = *(const float4*)(bias + (size_t)c * OUT_ + to * 8);
    float4 bv1 = *(const float4*)(bias + (size_t)c * OUT_ + to * 8 + 4);
    #pragma unroll
    for (int r = 0; r < 8; ++r) {
        size_t ob = (size_t)(bBase + tb * 8 + r) * (C_ * OUT_)
                  + (size_t)c * OUT_ + to * 8;
        f32x4_t o0 = {acc[r][0] + bv0.x, acc[r][1] + bv0.y,
                      acc[r][2] + bv0.z, acc[r][3] + bv0.w};
        f32x4_t o1 = {acc[r][4] + bv1.x, acc[r][5] + bv1.y,
                      acc[r][6] + bv1.z, acc[r][7] + bv1.w};
        __builtin_nontemporal_store(o0, (f32x4_t*)(out + ob));
        __builtin_nontemporal_store(o1, (f32x4_t*)(out + ob + 4));
    }
}

extern "C" void kernel_launch(void* const* d_in, const int* in_sizes, int n_in,
                              void* d_out, int out_size, void* d_ws, size_t ws_size,
                              hipStream_t stream) {
    const float* x    = (const float*)d_in[0];
    const float* k    = (const float*)d_in[1];
    const float* bias = (const float*)d_in[2];
    float* out        = (float*)d_out;

    const int B     = in_sizes[0] / (C_ * IN_);   // 8192
    const int tiles = B / BT;                     // 32
    dim3 grid(64 * tiles);                        // c = blk & 63, tile = blk >> 6
    cat_dense_f32<<<grid, 256, 0, stream>>>(x, k, bias, out);
}

// Round 4
// 54.026 us; speedup vs baseline: 2.1363x; 2.1363x over previous
//
#include <hip/hip_runtime.h>

// CategoryDense: out[b,c,o] = sum_i x[b,c,i] * kernel[c,i,o] + bias[c,o]
// B=8192, C=64, IN=64, OUT=64, fp32 in/out.
// MFMA version: bf16 convert in-register, mfma_f32_16x16x32_bf16, fp32 accum.
// Block = (category c, 256-batch tile), 4 waves; wave owns 64 batches in two
// M=32 passes. Only k[c] staged in LDS (16 KB fp32, global_load_lds). x reads
// go global->reg in A-fragment shape. ONE barrier total.

constexpr int C_   = 64;
constexpr int IN_  = 64;
constexpr int OUT_ = 64;
constexpr int BT   = 256;

typedef __attribute__((ext_vector_type(8))) short bf16x8;
typedef __attribute__((ext_vector_type(4))) float f32x4;

typedef __attribute__((address_space(1))) const void gvoid_t;
typedef __attribute__((address_space(3))) void lvoid_t;

__device__ __forceinline__ void gl_lds16(const float* g, float* l) {
    __builtin_amdgcn_global_load_lds((gvoid_t*)g, (lvoid_t*)l, 16, 0, 0);
}

__device__ __forceinline__ short f2bf(float f) {
    union { float f; unsigned u; } v; v.f = f;
    unsigned r = v.u + 0x7FFF + ((v.u >> 16) & 1);   // RNE
    return (short)(r >> 16);
}

__global__ __launch_bounds__(256)
void cat_dense_mfma(const float* __restrict__ x,
                    const float* __restrict__ k,
                    const float* __restrict__ bias,
                    float* __restrict__ out) {
    __shared__ float ksm[IN_ * OUT_];   // 16 KB, fp32 k[c] row-major [i][o]

    const int tid  = threadIdx.x;
    const int wv   = tid >> 6;
    const int lane = tid & 63;
    const int c    = blockIdx.x & 63;
    const long bBase = (long)(blockIdx.x >> 6) * BT;

    const int lrow = lane & 15;   // A row / B col / C col within 16-tile
    const int lkg  = lane >> 4;   // K-octet select; C row-group

    // ---- stage k[c] -> LDS (linear dest, coalesced src), 4 DMA per wave ----
    #pragma unroll
    for (int it = 0; it < 4; ++it) {
        int gb = wv * 256 + it * 64;   // wave-uniform granule base
        gl_lds16(k + (size_t)c * (IN_ * OUT_) + (size_t)(gb + lane) * 4,
                 &ksm[gb * 4]);
    }

    // ---- x -> A-fragments (global->reg->bf16), issued before the barrier ----
    // frag (p,mt,ks): row = bBase + wv*64 + p*32 + mt*16 + lrow,
    //                 k-elems = ks*32 + lkg*8 + j (j=0..7) -> 2x float4
    bf16x8 af[8];
    #pragma unroll
    for (int p = 0; p < 2; ++p)
      #pragma unroll
      for (int mt = 0; mt < 2; ++mt)
        #pragma unroll
        for (int ksi = 0; ksi < 2; ++ksi) {
            const float* xp = x
                + (size_t)(bBase + wv * 64 + p * 32 + mt * 16 + lrow) * (C_ * IN_)
                + (size_t)c * IN_ + ksi * 32 + lkg * 8;
            f32x4 lo = *(const f32x4*)xp;
            f32x4 hi = *(const f32x4*)(xp + 4);
            bf16x8 a;
            #pragma unroll
            for (int e = 0; e < 4; ++e) {
                a[e]     = f2bf(lo[e]);
                a[4 + e] = f2bf(hi[e]);
            }
            af[(p * 2 + mt) * 2 + ksi] = a;
        }

    // bias for this lane's 4 output columns
    float bv[4];
    #pragma unroll
    for (int nt = 0; nt < 4; ++nt)
        bv[nt] = bias[(size_t)c * OUT_ + nt * 16 + lrow];

    __syncthreads();   // k staged (barrier drains the gl_lds queue)

    // ---- B-fragments from LDS: col = nt*16+lrow, k = ks*32 + lkg*8 + j ----
    bf16x8 kb[4][2];
    #pragma unroll
    for (int nt = 0; nt < 4; ++nt)
      #pragma unroll
      for (int ksi = 0; ksi < 2; ++ksi) {
        bf16x8 b;
        #pragma unroll
        for (int j = 0; j < 8; ++j)
            b[j] = f2bf(ksm[(ksi * 32 + lkg * 8 + j) * OUT_ + nt * 16 + lrow]);
        kb[nt][ksi] = b;
      }

    // ---- compute + store: two passes of M=32 ----
    #pragma unroll
    for (int p = 0; p < 2; ++p) {
        f32x4 acc[2][4];
        #pragma unroll
        for (int mt = 0; mt < 2; ++mt)
          #pragma unroll
          for (int nt = 0; nt < 4; ++nt)
            acc[mt][nt] = (f32x4){0.f, 0.f, 0.f, 0.f};

        #pragma unroll
        for (int ksi = 0; ksi < 2; ++ksi)
          #pragma unroll
          for (int mt = 0; mt < 2; ++mt) {
            bf16x8 a = af[(p * 2 + mt) * 2 + ksi];
            #pragma unroll
            for (int nt = 0; nt < 4; ++nt)
                acc[mt][nt] = __builtin_amdgcn_mfma_f32_16x16x32_bf16(
                                  a, kb[nt][ksi], acc[mt][nt], 0, 0, 0);
          }

        // C layout: col = lane&15 (+nt*16), row = lkg*4 + reg (+p*32 + mt*16)
        #pragma unroll
        for (int mt = 0; mt < 2; ++mt) {
            size_t rbase = (size_t)(bBase + wv * 64 + p * 32 + mt * 16 + lkg * 4)
                               * (C_ * OUT_)
                         + (size_t)c * OUT_ + lrow;
            #pragma unroll
            for (int reg = 0; reg < 4; ++reg)
              #pragma unroll
              for (int nt = 0; nt < 4; ++nt)
                __builtin_nontemporal_store(
                    acc[mt][nt][reg] + bv[nt],
                    out + rbase + (size_t)reg * (C_ * OUT_) + nt * 16);
        }
    }
}

extern "C" void kernel_launch(void* const* d_in, const int* in_sizes, int n_in,
                              void* d_out, int out_size, void* d_ws, size_t ws_size,
                              hipStream_t stream) {
    const float* x    = (const float*)d_in[0];
    const float* k    = (const float*)d_in[1];
    const float* bias = (const float*)d_in[2];
    float* out        = (float*)d_out;

    const int B     = in_sizes[0] / (C_ * IN_);   // 8192
    const int tiles = B / BT;                     // 32
    dim3 grid(64 * tiles);                        // c = blk & 63, tile = blk >> 6
    cat_dense_mfma<<<grid, 256, 0, stream>>>(x, k, bias, out);
}